// Round 9
// baseline (722.632 us; speedup 1.0000x reference)
//
#include <hip/hip_runtime.h>
#include <stdint.h>

typedef unsigned short u16;
typedef unsigned int u32;

#define B_ 16
#define N_ 4096
#define S_ 512
#define D2_ 384
#define K_ 5
#define CIN 387
#define KP 416
#define M_ (B_*N_)

typedef float f32x4 __attribute__((ext_vector_type(4)));
typedef u32 u32x4 __attribute__((ext_vector_type(4)));
typedef __bf16 bf16x8 __attribute__((ext_vector_type(8)));

__device__ __forceinline__ float bf2f(u16 h) {
  union { u32 u; float f; } v; v.u = ((u32)h) << 16; return v.f;
}
__device__ __forceinline__ u16 f2bf(float f) {
  union { float f; u32 u; } v; v.f = f;
  u32 u = v.u;
  u32 r = (u + 0x7FFFu + ((u >> 16) & 1u)) >> 16;
  return (u16)r;
}

__device__ __forceinline__ float erf_approx(float x) {
  float ax = fabsf(x);
  float t = __builtin_amdgcn_rcpf(fmaf(0.3275911f, ax, 1.0f));
  float p = fmaf(t, 1.061405429f, -1.453152027f);
  p = fmaf(p, t, 1.421413741f);
  p = fmaf(p, t, -0.284496736f);
  p = fmaf(p, t, 0.254829592f);
  p = p * t;
  float e = __expf(-ax * ax);
  float r = fmaf(-p, e, 1.0f);
  return copysignf(r, x);
}

__device__ __forceinline__ float gelu_f(float y) {
  return 0.5f * y * (1.f + erf_approx(y * 0.70710678118654752f));
}

__device__ __forceinline__ void gld16(const void* g, void* l) {
  __builtin_amdgcn_global_load_lds(
      (const __attribute__((address_space(1))) unsigned int*)g,
      (__attribute__((address_space(3))) unsigned int*)l, 16, 0, 0);
}

// ---------------- prep: pad+permute W0, convert W1, zero stats ----------------
__global__ void prep_kernel(const float* __restrict__ W0, u16* __restrict__ W0p,
                            const float* __restrict__ W1, u16* __restrict__ W1c,
                            float* __restrict__ stats) {
  int bi = blockIdx.x;
  int tid = threadIdx.x;
  if (bi < 624) {
    int i = bi * 256 + tid;
    int r = i / KP, c = i - r * KP;
    float v = 0.f;
    if (c < 384)      v = W0[r * CIN + 3 + c];
    else if (c < CIN) v = W0[r * CIN + (c - 384)];
    W0p[i] = (c < CIN) ? f2bf(v) : (u16)0;
  } else if (bi < 1200) {
    int i = (bi - 624) * 256 + tid;
    W1c[i] = f2bf(W1[i]);
  } else {
    int i = (bi - 1200) * 256 + tid;
    if (i < 1536) stats[i] = 0.f;
  }
}

// ---------------- KNN (REP-templated for attribution probe) ----------------
template<int REP>
__global__ __launch_bounds__(256) void knn_kernel(
    const float* __restrict__ xyz1, const float* __restrict__ xyz2,
    const float* __restrict__ points1, const int* __restrict__ emb_lens,
    u16* __restrict__ A1, float* __restrict__ idx_out,
    float* __restrict__ wq, int* __restrict__ iq)
{
  __shared__ float4 sxyz[S_];
  __shared__ float sd[256][K_];
  __shared__ int   si[256][K_];

  int b = blockIdx.x >> 5;
  int n0 = (blockIdx.x & 31) << 7;
  int tid = threadIdx.x;

  #pragma unroll 1
  for (int rep = 0; rep < REP; ++rep) {
    const float* kb = xyz2 + (size_t)b * S_ * 3;
    for (int i = tid; i < S_; i += 256)
      sxyz[i] = make_float4(kb[3*i], kb[3*i+1], kb[3*i+2], 0.f);
    __syncthreads();

    int L = emb_lens[b];
    int q = tid & 127, chunk = tid >> 7;
    const float* qp = xyz1 + ((size_t)b * N_ + n0 + q) * 3;
    float qx = qp[0], qy = qp[1], qz = qp[2];

    float d0=3e38f, d1=3e38f, d2=3e38f, d3=3e38f, d4=3e38f;
    int   i0=0, i1=0, i2=0, i3=0, i4=0;
    int sbase = chunk << 8;
    #pragma unroll 4
    for (int t = 0; t < 256; ++t) {
      int s = sbase + t;
      float4 k4 = sxyz[s];
      float dx = __fsub_rn(qx, k4.x), dy = __fsub_rn(qy, k4.y), dz = __fsub_rn(qz, k4.z);
      float dd = __fadd_rn(__fadd_rn(__fmul_rn(dx,dx), __fmul_rn(dy,dy)),
                           __fmul_rn(dz,dz));
      if (s >= L) dd = 1e10f;
      if (dd < d4) {
        if (dd < d3) { d4=d3; i4=i3;
          if (dd < d2) { d3=d2; i3=i2;
            if (dd < d1) { d2=d1; i2=i1;
              if (dd < d0) { d1=d0; i1=i0; d0=dd; i0=s; }
              else         { d1=dd; i1=s; }
            } else { d2=dd; i2=s; }
          } else { d3=dd; i3=s; }
        } else { d4=dd; i4=s; }
      }
    }
    sd[tid][0]=d0; sd[tid][1]=d1; sd[tid][2]=d2; sd[tid][3]=d3; sd[tid][4]=d4;
    si[tid][0]=i0; si[tid][1]=i1; si[tid][2]=i2; si[tid][3]=i3; si[tid][4]=i4;
    __syncthreads();

    if (tid < 128) {
      float md[K_]; int mi[K_];
      int pa = 0, pb = 0;
      #pragma unroll
      for (int k = 0; k < K_; ++k) {
        float da_ = sd[tid][pa], db_ = sd[tid + 128][pb];
        bool ta = da_ <= db_;
        md[k] = ta ? da_ : db_;
        mi[k] = ta ? si[tid][pa] : si[tid + 128][pb];
        pa += ta ? 1 : 0; pb += ta ? 0 : 1;
      }
      float w[K_]; float ws = 0.f;
      #pragma unroll
      for (int k = 0; k < K_; ++k) { w[k] = 1.f / (md[k] + 1.1920929e-7f); ws += w[k]; }
      float inv = 1.f / ws;
      size_t row = (size_t)b * N_ + n0 + tid;
      #pragma unroll
      for (int k = 0; k < K_; ++k) {
        wq[row * K_ + k] = w[k] * inv;
        iq[row * K_ + k] = mi[k];
        idx_out[row * K_ + k] = (float)mi[k];
      }
      u16* rp = A1 + row * KP;
      const float* p1 = points1 + row * 3;
      rp[384] = f2bf(p1[0]); rp[385] = f2bf(p1[1]); rp[386] = f2bf(p1[2]);
      #pragma unroll
      for (int c = CIN; c < KP; ++c) rp[c] = 0;
    }
    __syncthreads();
  }
}

// ---------------- interpolation (REP-templated) ----------------
template<int REP>
__global__ __launch_bounds__(256) void interp_kernel(
    const float* __restrict__ points2,
    const float* __restrict__ wq, const int* __restrict__ iq,
    u16* __restrict__ A1)
{
  int lane = threadIdx.x & 63, wid = threadIdx.x >> 6;
  int i = blockIdx.x;
  int gq = ((i & 7) << 13) + ((i >> 3) << 2) + wid;
  int b = gq >> 12;

  #pragma unroll 1
  for (int rep = 0; rep < REP; ++rep) {
    float w[K_]; int id[K_];
    #pragma unroll
    for (int k = 0; k < K_; ++k) {
      w[k] = wq[(size_t)gq * K_ + k];
      id[k] = iq[(size_t)gq * K_ + k];
    }
    const float* p2 = points2 + (size_t)b * S_ * D2_;
    const float2* r0 = (const float2*)(p2 + (size_t)id[0] * D2_);
    const float2* r1 = (const float2*)(p2 + (size_t)id[1] * D2_);
    const float2* r2 = (const float2*)(p2 + (size_t)id[2] * D2_);
    const float2* r3 = (const float2*)(p2 + (size_t)id[3] * D2_);
    const float2* r4 = (const float2*)(p2 + (size_t)id[4] * D2_);
    u16* rp = A1 + (size_t)gq * KP;
    #pragma unroll
    for (int j = 0; j < 3; ++j) {
      int c2 = j * 64 + lane;
      float2 v0 = r0[c2], v1 = r1[c2], v2 = r2[c2], v3 = r3[c2], v4 = r4[c2];
      float a0 = w[0]*v0.x + w[1]*v1.x + w[2]*v2.x + w[3]*v3.x + w[4]*v4.x;
      float a1 = w[0]*v0.y + w[1]*v1.y + w[2]*v2.y + w[3]*v3.y + w[4]*v4.y;
      u32 pack = (u32)f2bf(a0) | ((u32)f2bf(a1) << 16);
      *(u32*)(rp + c2 * 2) = pack;
    }
  }
}

// ---------------- NT GEMM + fused masked BN stats (unchanged, known-good) ----------------
template<bool F32OUT, int KT>
__global__ __launch_bounds__(256) void gemm_nt_kernel(
    const u16* __restrict__ A, int lda,
    const u16* __restrict__ W, int ldw,
    void* __restrict__ Cv, int ldc,
    const int* __restrict__ lens, float* __restrict__ sums)
{
  __shared__ __align__(16) u16 sA[2][128 * 32];
  __shared__ __align__(16) u16 sB[2][128 * 32];
  __shared__ float lsum[128], lsq[128];
  int tid = threadIdx.x;
  int lane = tid & 63, wid = tid >> 6;
  u32 bi = blockIdx.x;
  u32 s = bi >> 3;
  int m0 = (int)(((bi & 7) * 64 + s / 3) * 128);
  int n0 = (int)((s % 3) * 128);
  int wm = (wid & 1) * 64, wn = (wid >> 1) * 64;
  int frow = lane & 15, quad = lane >> 4;

  if (tid < 128) { lsum[tid] = 0.f; lsq[tid] = 0.f; }

  int grow = wid * 16 + (lane >> 2);
  int cq = (lane & 3) * 8;
  const u16* gA0 = A + (size_t)(m0 + grow) * lda + cq;
  const u16* gA1 = gA0 + (size_t)64 * lda;
  const u16* gB0 = W + (size_t)(n0 + grow) * ldw + cq;
  const u16* gB1 = gB0 + (size_t)64 * ldw;

  f32x4 acc[4][4];
  f32x4 zero4 = {0.f, 0.f, 0.f, 0.f};
  #pragma unroll
  for (int i = 0; i < 4; ++i)
    #pragma unroll
    for (int j = 0; j < 4; ++j) acc[i][j] = zero4;

  gld16(gA0, sA[0] + wid * 512); gld16(gA1, sA[0] + (wid + 4) * 512);
  gld16(gB0, sB[0] + wid * 512); gld16(gB1, sB[0] + (wid + 4) * 512);
  gA0 += 32; gA1 += 32; gB0 += 32; gB1 += 32;

  #pragma unroll
  for (int kt = 0; kt < KT; ++kt) {
    __syncthreads();
    int p = kt & 1;
    if (kt + 1 < KT) {
      int np = p ^ 1;
      gld16(gA0, sA[np] + wid * 512); gld16(gA1, sA[np] + (wid + 4) * 512);
      gld16(gB0, sB[np] + wid * 512); gld16(gB1, sB[np] + (wid + 4) * 512);
      gA0 += 32; gA1 += 32; gB0 += 32; gB1 += 32;
    }
    bf16x8 af[4], bfr[4];
    #pragma unroll
    for (int i = 0; i < 4; ++i)
      af[i] = *(const bf16x8*)(sA[p] + (wm + i * 16 + frow) * 32 + quad * 8);
    #pragma unroll
    for (int j = 0; j < 4; ++j)
      bfr[j] = *(const bf16x8*)(sB[p] + (wn + j * 16 + frow) * 32 + quad * 8);
    #pragma unroll
    for (int i = 0; i < 4; ++i)
      #pragma unroll
      for (int j = 0; j < 4; ++j)
        acc[i][j] = __builtin_amdgcn_mfma_f32_16x16x32_bf16(af[i], bfr[j], acc[i][j], 0, 0, 0);
  }

  int len = lens[m0 >> 12];
  float colS[4] = {0,0,0,0}, colQ[4] = {0,0,0,0};
  #pragma unroll
  for (int i = 0; i < 4; ++i) {
    #pragma unroll
    for (int j = 0; j < 4; ++j) {
      int col = n0 + wn + j * 16 + frow;
      #pragma unroll
      for (int r = 0; r < 4; ++r) {
        int m = m0 + wm + i * 16 + quad * 4 + r;
        float v = acc[i][j][r];
        if constexpr (F32OUT) ((float*)Cv)[(size_t)m * ldc + col] = v;
        else                  ((u16*)Cv)[(size_t)m * ldc + col] = f2bf(v);
        float x = ((m & 4095) < len) ? v : 0.f;
        colS[j] += x; colQ[j] += x * x;
      }
    }
  }
  #pragma unroll
  for (int j = 0; j < 4; ++j) {
    colS[j] += __shfl_xor(colS[j], 16); colS[j] += __shfl_xor(colS[j], 32);
    colQ[j] += __shfl_xor(colQ[j], 16); colQ[j] += __shfl_xor(colQ[j], 32);
    if (lane < 16) {
      int cl = wn + j * 16 + frow;
      atomicAdd(&lsum[cl], colS[j]);
      atomicAdd(&lsq[cl], colQ[j]);
    }
  }
  __syncthreads();
  if (tid < 128) {
    atomicAdd(&sums[n0 + tid], lsum[tid]);
    atomicAdd(&sums[384 + n0 + tid], lsq[tid]);
  }
}

// ---------------- per-block BN finalize into LDS ----------------
__device__ __forceinline__ void finalize_to_lds(
    float* spar, const float* __restrict__ sums,
    const float* __restrict__ gamma, const float* __restrict__ beta,
    const int* __restrict__ lens, int tid)
{
  float nv = 0.f;
  #pragma unroll
  for (int b = 0; b < B_; ++b) nv += (float)lens[b];
  for (int c = tid; c < 384; c += 256) {
    float mean = sums[c] / nv;
    float var = sums[384 + c] / nv - mean * mean;
    var = fmaxf(var, 0.f);
    float rstd = rsqrtf(var + 1e-5f);
    float a = rstd * gamma[c];
    spar[c] = a;
    spar[384 + c] = beta[c] - mean * a;
  }
  __syncthreads();
}

// ---------------- apply BN + GELU, separate src/dst (REP-templated) ----------------
// Real call: Xin==Xout (in place, REP=1). Probe call: Xout = dead scratch.
// No __restrict__ on Xin/Xout (they alias in the real call).
template<int REP>
__global__ __launch_bounds__(256) void apply_bn_gelu_kernel(
    const u16* Xin, u16* Xout, const float* __restrict__ sums,
    const float* __restrict__ gamma, const float* __restrict__ beta,
    const int* __restrict__ lens)
{
  __shared__ float spar[768];
  int tid = threadIdx.x;
  finalize_to_lds(spar, sums, gamma, beta, lens, tid);

  int t = blockIdx.x * 256 + tid;
  int half = t >= 196608;
  int tt = t - half * 196608;
  int r0 = tt / 48;
  int c0 = (tt - r0 * 48) * 8;
  float a[8], bb[8];
  #pragma unroll
  for (int j = 0; j < 8; ++j) { a[j] = spar[c0 + j]; bb[j] = spar[384 + c0 + j]; }

  const size_t rstride = (size_t)4096 * D2_;
  size_t off = (size_t)r0 * D2_ + c0 + (size_t)half * 8 * rstride;

  #pragma unroll 1
  for (int rep = 0; rep < REP; ++rep) {
    u32x4 v[8];
    #pragma unroll
    for (int it = 0; it < 8; ++it)
      v[it] = *(const u32x4*)(Xin + off + (size_t)it * rstride);
    #pragma unroll
    for (int it = 0; it < 8; ++it) {
      const u16* h = (const u16*)&v[it];
      u32x4 o; u16* ho = (u16*)&o;
      #pragma unroll
      for (int j = 0; j < 8; ++j) {
        float y = fmaf(bf2f(h[j]), a[j], bb[j]);
        ho[j] = f2bf(gelu_f(y));
      }
      *(u32x4*)(Xout + off + (size_t)it * rstride) = o;
    }
  }
}

// ---------------- apply BN (masked): bf16 x1 -> f32 out (REP-templated) ----------------
template<int REP>
__global__ __launch_bounds__(256) void apply_bn_out_kernel(
    const u16* __restrict__ X, const float* __restrict__ sums,
    const float* __restrict__ gamma, const float* __restrict__ beta,
    const int* __restrict__ lens, float* __restrict__ out)
{
  __shared__ float spar[768];
  int tid = threadIdx.x;
  finalize_to_lds(spar, sums, gamma, beta, lens, tid);

  int t = blockIdx.x * 256 + tid;
  int half = t >= 196608;
  int tt = t - half * 196608;
  int r0 = tt / 48;
  int c0 = (tt - r0 * 48) * 8;
  float a[8], bb[8];
  #pragma unroll
  for (int j = 0; j < 8; ++j) { a[j] = spar[c0 + j]; bb[j] = spar[384 + c0 + j]; }

  const size_t rstride = (size_t)4096 * D2_;
  const u16* src = X + (size_t)r0 * D2_ + c0 + (size_t)half * 8 * rstride;
  float* dst = out + (size_t)r0 * D2_ + c0 + (size_t)half * 8 * rstride;

  #pragma unroll 1
  for (int rep = 0; rep < REP; ++rep) {
    u32x4 v[8];
    #pragma unroll
    for (int it = 0; it < 8; ++it)
      v[it] = *(const u32x4*)(src + (size_t)it * rstride);
    #pragma unroll
    for (int it = 0; it < 8; ++it) {
      int b = half * 8 + it;
      bool valid = r0 < lens[b];
      const u16* h = (const u16*)&v[it];
      f32x4 o0, o1;
      #pragma unroll
      for (int j = 0; j < 4; ++j) {
        float y = fmaf(bf2f(h[j]), a[j], bb[j]);
        o0[j] = valid ? y : 0.f;
      }
      #pragma unroll
      for (int j = 0; j < 4; ++j) {
        float y = fmaf(bf2f(h[4 + j]), a[4 + j], bb[4 + j]);
        o1[j] = valid ? y : 0.f;
      }
      float* op = dst + (size_t)it * rstride;
      __builtin_nontemporal_store(o0, (f32x4*)op);
      __builtin_nontemporal_store(o1, (f32x4*)(op + 4));
    }
  }
}

extern "C" void kernel_launch(void* const* d_in, const int* in_sizes, int n_in,
                              void* d_out, int out_size, void* d_ws, size_t ws_size,
                              hipStream_t stream) {
  const float* xyz1    = (const float*)d_in[0];
  const float* xyz2    = (const float*)d_in[1];
  const float* points1 = (const float*)d_in[2];
  const float* points2 = (const float*)d_in[3];
  const int* point_lens = (const int*)d_in[4];
  const int* emb_lens   = (const int*)d_in[5];
  const float* W0 = (const float*)d_in[7];
  const float* g0 = (const float*)d_in[8];
  const float* b0 = (const float*)d_in[9];
  const float* W1 = (const float*)d_in[10];
  const float* g1 = (const float*)d_in[11];
  const float* b1 = (const float*)d_in[12];

  float* out = (float*)d_out;
  float* idx_out = out + (size_t)M_ * D2_;

  char* w = (char*)d_ws;
  u16* A1    = (u16*)w;                       // 65536 x 416 bf16
  u16* x1    = (u16*)w;                       // overlays A1 (dead after gemm1)
  u16* scratch = (u16*)w;                     // gelu-probe dump (A1 dead then;
                                              // gemm2 rewrites all of x1 after)
  u16* W0p   = (u16*)(w + 54525952);
  u16* W1c   = (u16*)(w + 54845440);
  u16* x0    = (u16*)(w + 55140352);
  float* wq  = (float*)(w + 55140352);
  int*   iq  = (int*)(w + 56451072);
  float* stats = (float*)(w + 105472000);

  prep_kernel<<<1212, 256, 0, stream>>>(W0, W0p, W1, W1c, stats);

  // === ATTRIBUTION PROBES: REP-looped duplicates; each dispatch > ~60us
  // enters rocprof top-5 with real counters. All bitwise-idempotent. ===
  knn_kernel<6><<<512, 256, 0, stream>>>(xyz1, xyz2, points1, emb_lens,
                                         A1, idx_out, wq, iq);       // PROBE
  knn_kernel<1><<<512, 256, 0, stream>>>(xyz1, xyz2, points1, emb_lens,
                                         A1, idx_out, wq, iq);       // real
  interp_kernel<6><<<16384, 256, 0, stream>>>(points2, wq, iq, A1);  // PROBE
  interp_kernel<1><<<16384, 256, 0, stream>>>(points2, wq, iq, A1);  // real
  gemm_nt_kernel<false, 13><<<1536, 256, 0, stream>>>(
      A1, KP, W0p, KP, x0, D2_, point_lens, stats);
  apply_bn_gelu_kernel<4><<<1536, 256, 0, stream>>>(
      x0, scratch, stats, g0, b0, point_lens);                       // PROBE
  apply_bn_gelu_kernel<1><<<1536, 256, 0, stream>>>(
      x0, x0, stats, g0, b0, point_lens);                            // real
  gemm_nt_kernel<false, 12><<<1536, 256, 0, stream>>>(
      x0, D2_, W1c, D2_, x1, D2_, point_lens, stats + 768);
  apply_bn_out_kernel<4><<<1536, 256, 0, stream>>>(
      x1, stats + 768, g1, b1, point_lens, out);                     // PROBE
  apply_bn_out_kernel<1><<<1536, 256, 0, stream>>>(
      x1, stats + 768, g1, b1, point_lens, out);                     // real
}

// Round 10
// 337.998 us; speedup vs baseline: 2.1380x; 2.1380x over previous
//
#include <hip/hip_runtime.h>
#include <stdint.h>

typedef unsigned short u16;
typedef unsigned int u32;

#define B_ 16
#define N_ 4096
#define S_ 512
#define D2_ 384
#define K_ 5
#define CIN 387
#define KP 416
#define M_ (B_*N_)

// ---- A1 / W0p column layout (permuted, both sides consistently) ----
// cols [0,384): interp features (4B-aligned); [384,387): points1; [387,416): pad

typedef float f32x4 __attribute__((ext_vector_type(4)));
typedef u32 u32x4 __attribute__((ext_vector_type(4)));
typedef __bf16 bf16x8 __attribute__((ext_vector_type(8)));

__device__ __forceinline__ float bf2f(u16 h) {
  union { u32 u; float f; } v; v.u = ((u32)h) << 16; return v.f;
}
__device__ __forceinline__ u16 f2bf(float f) {
  union { float f; u32 u; } v; v.f = f;
  u32 u = v.u;
  u32 r = (u + 0x7FFFu + ((u >> 16) & 1u)) >> 16;
  return (u16)r;
}

__device__ __forceinline__ float erf_approx(float x) {
  float ax = fabsf(x);
  float t = __builtin_amdgcn_rcpf(fmaf(0.3275911f, ax, 1.0f));
  float p = fmaf(t, 1.061405429f, -1.453152027f);
  p = fmaf(p, t, 1.421413741f);
  p = fmaf(p, t, -0.284496736f);
  p = fmaf(p, t, 0.254829592f);
  p = p * t;
  float e = __expf(-ax * ax);
  float r = fmaf(-p, e, 1.0f);
  return copysignf(r, x);
}

__device__ __forceinline__ float gelu_f(float y) {
  return 0.5f * y * (1.f + erf_approx(y * 0.70710678118654752f));
}

__device__ __forceinline__ void gld16(const void* g, void* l) {
  __builtin_amdgcn_global_load_lds(
      (const __attribute__((address_space(1))) unsigned int*)g,
      (__attribute__((address_space(3))) unsigned int*)l, 16, 0, 0);
}

// ---------------- prep: pad+permute W0, convert W1, zero stats ----------------
__global__ void prep_kernel(const float* __restrict__ W0, u16* __restrict__ W0p,
                            const float* __restrict__ W1, u16* __restrict__ W1c,
                            float* __restrict__ stats) {
  int bi = blockIdx.x;
  int tid = threadIdx.x;
  if (bi < 624) {
    int i = bi * 256 + tid;
    int r = i / KP, c = i - r * KP;
    float v = 0.f;
    if (c < 384)      v = W0[r * CIN + 3 + c];
    else if (c < CIN) v = W0[r * CIN + (c - 384)];
    W0p[i] = (c < CIN) ? f2bf(v) : (u16)0;
  } else if (bi < 1200) {
    int i = (bi - 624) * 256 + tid;
    W1c[i] = f2bf(W1[i]);
  } else {
    int i = (bi - 1200) * 256 + tid;
    if (i < 1536) stats[i] = 0.f;
  }
}

// ---------------- KNN: 4 key-chunks x 128, 64 queries/block, 1024 blocks ----------------
// R9 probe: old 2-chunk/512-block version = 46us, VALUBusy 52%, occ 21.6%
// (2 blk/CU). Cause: ~54 cyc/key-iter/wave (divergent nested insertion) x 256
// iters with only 8 waves/CU to overlap. This version halves per-thread iters
// (128) and doubles blocks/CU (4 -> 16 waves/CU).
__global__ __launch_bounds__(256) void knn_kernel(
    const float* __restrict__ xyz1, const float* __restrict__ xyz2,
    const float* __restrict__ points1, const int* __restrict__ emb_lens,
    u16* __restrict__ A1, float* __restrict__ idx_out,
    float* __restrict__ wq, int* __restrict__ iq)
{
  __shared__ float4 sxyz[S_];     // 8 KB
  __shared__ float sd[256][K_];   // 5 KB
  __shared__ int   si[256][K_];   // 5 KB

  int b = blockIdx.x >> 6;              // 64 blocks per batch
  int n0 = (blockIdx.x & 63) << 6;      // 64 queries per block
  int tid = threadIdx.x;

  const float* kb = xyz2 + (size_t)b * S_ * 3;
  for (int i = tid; i < S_; i += 256)
    sxyz[i] = make_float4(kb[3*i], kb[3*i+1], kb[3*i+2], 0.f);
  __syncthreads();

  int L = emb_lens[b];
  int q = tid & 63, chunk = tid >> 6;   // chunk == wave id, wave-uniform
  const float* qp = xyz1 + ((size_t)b * N_ + n0 + q) * 3;
  float qx = qp[0], qy = qp[1], qz = qp[2];

  float d0=3e38f, d1=3e38f, d2=3e38f, d3=3e38f, d4=3e38f;
  int   i0=0, i1=0, i2=0, i3=0, i4=0;
  int sbase = chunk << 7;               // 128 keys per chunk
  #pragma unroll 4
  for (int t = 0; t < 128; ++t) {
    int s = sbase + t;
    float4 k4 = sxyz[s];                // wave-uniform addr -> LDS broadcast
    // exact numpy association, no FMA contraction -> bitwise-identical d2
    float dx = __fsub_rn(qx, k4.x), dy = __fsub_rn(qy, k4.y), dz = __fsub_rn(qz, k4.z);
    float dd = __fadd_rn(__fadd_rn(__fmul_rn(dx,dx), __fmul_rn(dy,dy)),
                         __fmul_rn(dz,dz));
    if (s >= L) dd = 1e10f;
    if (dd < d4) {                      // strict < keeps stable (lowest-index) ties
      if (dd < d3) { d4=d3; i4=i3;
        if (dd < d2) { d3=d2; i3=i2;
          if (dd < d1) { d2=d1; i2=i1;
            if (dd < d0) { d1=d0; i1=i0; d0=dd; i0=s; }
            else         { d1=dd; i1=s; }
          } else { d2=dd; i2=s; }
        } else { d3=dd; i3=s; }
      } else { d4=dd; i4=s; }
    }
  }
  sd[tid][0]=d0; sd[tid][1]=d1; sd[tid][2]=d2; sd[tid][3]=d3; sd[tid][4]=d4;
  si[tid][0]=i0; si[tid][1]=i1; si[tid][2]=i2; si[tid][3]=i3; si[tid][4]=i4;
  __syncthreads();

  if (tid < 64) {
    // branch-free 4-way merge of sorted 5-lists (rows tid + 64*c).
    // Ties: lower chunk wins (strict < when higher challenges) -> lowest
    // global index, since chunks are contiguous index ranges.
    int p0 = 0, p1 = 0, p2 = 0, p3 = 0;
    float md[K_]; int mi[K_];
    #pragma unroll
    for (int k = 0; k < K_; ++k) {
      float a0 = sd[tid][p0],       a1 = sd[tid + 64][p1];
      float a2 = sd[tid + 128][p2], a3 = sd[tid + 192][p3];
      bool s01 = a1 < a0;                 // ties keep chunk0
      bool s23 = a3 < a2;                 // ties keep chunk2
      float m01 = s01 ? a1 : a0;
      float m23 = s23 ? a3 : a2;
      bool shi = m23 < m01;               // ties keep lower pair
      int r0 = s01 ? si[tid + 64][p1]  : si[tid][p0];
      int r1 = s23 ? si[tid + 192][p3] : si[tid + 128][p2];
      md[k] = shi ? m23 : m01;
      mi[k] = shi ? r1 : r0;
      p0 += (!shi && !s01); p1 += (!shi && s01);
      p2 += (shi && !s23);  p3 += (shi && s23);
    }
    float w[K_]; float ws = 0.f;
    #pragma unroll
    for (int k = 0; k < K_; ++k) { w[k] = 1.f / (md[k] + 1.1920929e-7f); ws += w[k]; }
    float inv = 1.f / ws;
    size_t row = (size_t)b * N_ + n0 + tid;
    #pragma unroll
    for (int k = 0; k < K_; ++k) {
      wq[row * K_ + k] = w[k] * inv;
      iq[row * K_ + k] = mi[k];
      idx_out[row * K_ + k] = (float)mi[k];
    }
    // A1 row suffix: points1 at cols 384..386 + zero pad 387..415
    u16* rp = A1 + row * KP;
    const float* p1v = points1 + row * 3;
    rp[384] = f2bf(p1v[0]); rp[385] = f2bf(p1v[1]); rp[386] = f2bf(p1v[2]);
    #pragma unroll
    for (int c = CIN; c < KP; ++c) rp[c] = 0;
  }
}

// ---------------- interpolation: one wave per query, float2 columns ----------------
__global__ __launch_bounds__(256) void interp_kernel(
    const float* __restrict__ points2,
    const float* __restrict__ wq, const int* __restrict__ iq,
    u16* __restrict__ A1)
{
  int lane = threadIdx.x & 63, wid = threadIdx.x >> 6;
  int i = blockIdx.x;                                  // 16384 blocks
  int gq = ((i & 7) << 13) + ((i >> 3) << 2) + wid;    // wave-uniform query id
  int b = gq >> 12;

  float w[K_]; int id[K_];
  #pragma unroll
  for (int k = 0; k < K_; ++k) {
    w[k] = wq[(size_t)gq * K_ + k];
    id[k] = iq[(size_t)gq * K_ + k];
  }
  const float* p2 = points2 + (size_t)b * S_ * D2_;
  const float2* r0 = (const float2*)(p2 + (size_t)id[0] * D2_);
  const float2* r1 = (const float2*)(p2 + (size_t)id[1] * D2_);
  const float2* r2 = (const float2*)(p2 + (size_t)id[2] * D2_);
  const float2* r3 = (const float2*)(p2 + (size_t)id[3] * D2_);
  const float2* r4 = (const float2*)(p2 + (size_t)id[4] * D2_);
  u16* rp = A1 + (size_t)gq * KP;
  #pragma unroll
  for (int j = 0; j < 3; ++j) {
    int c2 = j * 64 + lane;
    float2 v0 = r0[c2], v1 = r1[c2], v2 = r2[c2], v3 = r3[c2], v4 = r4[c2];
    float a0 = w[0]*v0.x + w[1]*v1.x + w[2]*v2.x + w[3]*v3.x + w[4]*v4.x;
    float a1 = w[0]*v0.y + w[1]*v1.y + w[2]*v2.y + w[3]*v3.y + w[4]*v4.y;
    u32 pack = (u32)f2bf(a0) | ((u32)f2bf(a1) << 16);
    *(u32*)(rp + c2 * 2) = pack;
  }
}

// ---------------- NT GEMM + fused masked BN stats (known-good) ----------------
template<bool F32OUT, int KT>
__global__ __launch_bounds__(256) void gemm_nt_kernel(
    const u16* __restrict__ A, int lda,
    const u16* __restrict__ W, int ldw,
    void* __restrict__ Cv, int ldc,
    const int* __restrict__ lens, float* __restrict__ sums)
{
  __shared__ __align__(16) u16 sA[2][128 * 32];
  __shared__ __align__(16) u16 sB[2][128 * 32];
  __shared__ float lsum[128], lsq[128];
  int tid = threadIdx.x;
  int lane = tid & 63, wid = tid >> 6;
  u32 bi = blockIdx.x;
  u32 s = bi >> 3;
  int m0 = (int)(((bi & 7) * 64 + s / 3) * 128);
  int n0 = (int)((s % 3) * 128);
  int wm = (wid & 1) * 64, wn = (wid >> 1) * 64;
  int frow = lane & 15, quad = lane >> 4;

  if (tid < 128) { lsum[tid] = 0.f; lsq[tid] = 0.f; }

  int grow = wid * 16 + (lane >> 2);
  int cq = (lane & 3) * 8;
  const u16* gA0 = A + (size_t)(m0 + grow) * lda + cq;
  const u16* gA1 = gA0 + (size_t)64 * lda;
  const u16* gB0 = W + (size_t)(n0 + grow) * ldw + cq;
  const u16* gB1 = gB0 + (size_t)64 * ldw;

  f32x4 acc[4][4];
  f32x4 zero4 = {0.f, 0.f, 0.f, 0.f};
  #pragma unroll
  for (int i = 0; i < 4; ++i)
    #pragma unroll
    for (int j = 0; j < 4; ++j) acc[i][j] = zero4;

  gld16(gA0, sA[0] + wid * 512); gld16(gA1, sA[0] + (wid + 4) * 512);
  gld16(gB0, sB[0] + wid * 512); gld16(gB1, sB[0] + (wid + 4) * 512);
  gA0 += 32; gA1 += 32; gB0 += 32; gB1 += 32;

  #pragma unroll
  for (int kt = 0; kt < KT; ++kt) {
    __syncthreads();
    int p = kt & 1;
    if (kt + 1 < KT) {
      int np = p ^ 1;
      gld16(gA0, sA[np] + wid * 512); gld16(gA1, sA[np] + (wid + 4) * 512);
      gld16(gB0, sB[np] + wid * 512); gld16(gB1, sB[np] + (wid + 4) * 512);
      gA0 += 32; gA1 += 32; gB0 += 32; gB1 += 32;
    }
    bf16x8 af[4], bfr[4];
    #pragma unroll
    for (int i = 0; i < 4; ++i)
      af[i] = *(const bf16x8*)(sA[p] + (wm + i * 16 + frow) * 32 + quad * 8);
    #pragma unroll
    for (int j = 0; j < 4; ++j)
      bfr[j] = *(const bf16x8*)(sB[p] + (wn + j * 16 + frow) * 32 + quad * 8);
    #pragma unroll
    for (int i = 0; i < 4; ++i)
      #pragma unroll
      for (int j = 0; j < 4; ++j)
        acc[i][j] = __builtin_amdgcn_mfma_f32_16x16x32_bf16(af[i], bfr[j], acc[i][j], 0, 0, 0);
  }

  int len = lens[m0 >> 12];
  float colS[4] = {0,0,0,0}, colQ[4] = {0,0,0,0};
  #pragma unroll
  for (int i = 0; i < 4; ++i) {
    #pragma unroll
    for (int j = 0; j < 4; ++j) {
      int col = n0 + wn + j * 16 + frow;
      #pragma unroll
      for (int r = 0; r < 4; ++r) {
        int m = m0 + wm + i * 16 + quad * 4 + r;
        float v = acc[i][j][r];
        if constexpr (F32OUT) ((float*)Cv)[(size_t)m * ldc + col] = v;
        else                  ((u16*)Cv)[(size_t)m * ldc + col] = f2bf(v);
        float x = ((m & 4095) < len) ? v : 0.f;
        colS[j] += x; colQ[j] += x * x;
      }
    }
  }
  #pragma unroll
  for (int j = 0; j < 4; ++j) {
    colS[j] += __shfl_xor(colS[j], 16); colS[j] += __shfl_xor(colS[j], 32);
    colQ[j] += __shfl_xor(colQ[j], 16); colQ[j] += __shfl_xor(colQ[j], 32);
    if (lane < 16) {
      int cl = wn + j * 16 + frow;
      atomicAdd(&lsum[cl], colS[j]);
      atomicAdd(&lsq[cl], colQ[j]);
    }
  }
  __syncthreads();
  if (tid < 128) {
    atomicAdd(&sums[n0 + tid], lsum[tid]);
    atomicAdd(&sums[384 + n0 + tid], lsq[tid]);
  }
}

// ---------------- per-block BN finalize into LDS ----------------
__device__ __forceinline__ void finalize_to_lds(
    float* spar, const float* __restrict__ sums,
    const float* __restrict__ gamma, const float* __restrict__ beta,
    const int* __restrict__ lens, int tid)
{
  float nv = 0.f;
  #pragma unroll
  for (int b = 0; b < B_; ++b) nv += (float)lens[b];
  for (int c = tid; c < 384; c += 256) {
    float mean = sums[c] / nv;
    float var = sums[384 + c] / nv - mean * mean;
    var = fmaxf(var, 0.f);
    float rstd = rsqrtf(var + 1e-5f);
    float a = rstd * gamma[c];
    spar[c] = a;
    spar[384 + c] = beta[c] - mean * a;
  }
  __syncthreads();
}

// ---------------- apply BN + GELU (in place on bf16 x0), fused finalize ----------------
__global__ __launch_bounds__(256) void apply_bn_gelu_kernel(
    u16* __restrict__ X, const float* __restrict__ sums,
    const float* __restrict__ gamma, const float* __restrict__ beta,
    const int* __restrict__ lens)
{
  __shared__ float spar[768];
  int tid = threadIdx.x;
  finalize_to_lds(spar, sums, gamma, beta, lens, tid);

  int t = blockIdx.x * 256 + tid;
  int half = t >= 196608;
  int tt = t - half * 196608;
  int r0 = tt / 48;
  int c0 = (tt - r0 * 48) * 8;
  float a[8], bb[8];
  #pragma unroll
  for (int j = 0; j < 8; ++j) { a[j] = spar[c0 + j]; bb[j] = spar[384 + c0 + j]; }

  const size_t rstride = (size_t)4096 * D2_;
  u16* base = X + (size_t)r0 * D2_ + c0 + (size_t)half * 8 * rstride;

  u32x4 v[8];
  #pragma unroll
  for (int it = 0; it < 8; ++it)
    v[it] = *(const u32x4*)(base + (size_t)it * rstride);
  #pragma unroll
  for (int it = 0; it < 8; ++it) {
    const u16* h = (const u16*)&v[it];
    u32x4 o; u16* ho = (u16*)&o;
    #pragma unroll
    for (int j = 0; j < 8; ++j) {
      float y = fmaf(bf2f(h[j]), a[j], bb[j]);
      ho[j] = f2bf(gelu_f(y));
    }
    *(u32x4*)(base + (size_t)it * rstride) = o;
  }
}

// ---------------- apply BN (masked): bf16 x1 -> f32 out, fused finalize ----------------
__global__ __launch_bounds__(256) void apply_bn_out_kernel(
    const u16* __restrict__ X, const float* __restrict__ sums,
    const float* __restrict__ gamma, const float* __restrict__ beta,
    const int* __restrict__ lens, float* __restrict__ out)
{
  __shared__ float spar[768];
  int tid = threadIdx.x;
  finalize_to_lds(spar, sums, gamma, beta, lens, tid);

  int t = blockIdx.x * 256 + tid;
  int half = t >= 196608;
  int tt = t - half * 196608;
  int r0 = tt / 48;
  int c0 = (tt - r0 * 48) * 8;
  float a[8], bb[8];
  #pragma unroll
  for (int j = 0; j < 8; ++j) { a[j] = spar[c0 + j]; bb[j] = spar[384 + c0 + j]; }

  const size_t rstride = (size_t)4096 * D2_;
  const u16* src = X + (size_t)r0 * D2_ + c0 + (size_t)half * 8 * rstride;
  float* dst = out + (size_t)r0 * D2_ + c0 + (size_t)half * 8 * rstride;

  u32x4 v[8];
  #pragma unroll
  for (int it = 0; it < 8; ++it)
    v[it] = *(const u32x4*)(src + (size_t)it * rstride);
  #pragma unroll
  for (int it = 0; it < 8; ++it) {
    int b = half * 8 + it;
    bool valid = r0 < lens[b];
    const u16* h = (const u16*)&v[it];
    f32x4 o0, o1;
    #pragma unroll
    for (int j = 0; j < 4; ++j) {
      float y = fmaf(bf2f(h[j]), a[j], bb[j]);
      o0[j] = valid ? y : 0.f;
    }
    #pragma unroll
    for (int j = 0; j < 4; ++j) {
      float y = fmaf(bf2f(h[4 + j]), a[4 + j], bb[4 + j]);
      o1[j] = valid ? y : 0.f;
    }
    float* op = dst + (size_t)it * rstride;
    __builtin_nontemporal_store(o0, (f32x4*)op);
    __builtin_nontemporal_store(o1, (f32x4*)(op + 4));
  }
}

extern "C" void kernel_launch(void* const* d_in, const int* in_sizes, int n_in,
                              void* d_out, int out_size, void* d_ws, size_t ws_size,
                              hipStream_t stream) {
  const float* xyz1    = (const float*)d_in[0];
  const float* xyz2    = (const float*)d_in[1];
  const float* points1 = (const float*)d_in[2];
  const float* points2 = (const float*)d_in[3];
  const int* point_lens = (const int*)d_in[4];
  const int* emb_lens   = (const int*)d_in[5];
  const float* W0 = (const float*)d_in[7];
  const float* g0 = (const float*)d_in[8];
  const float* b0 = (const float*)d_in[9];
  const float* W1 = (const float*)d_in[10];
  const float* g1 = (const float*)d_in[11];
  const float* b1 = (const float*)d_in[12];

  float* out = (float*)d_out;
  float* idx_out = out + (size_t)M_ * D2_;

  char* w = (char*)d_ws;
  u16* A1    = (u16*)w;                       // 65536 x 416 bf16
  u16* x1    = (u16*)w;                       // overlays A1 (dead after gemm1)
  u16* W0p   = (u16*)(w + 54525952);
  u16* W1c   = (u16*)(w + 54845440);
  u16* x0    = (u16*)(w + 55140352);
  float* wq  = (float*)(w + 55140352);
  int*   iq  = (int*)(w + 56451072);
  float* stats = (float*)(w + 105472000);

  prep_kernel<<<1206, 256, 0, stream>>>(W0, W0p, W1, W1c, stats);
  knn_kernel<<<1024, 256, 0, stream>>>(xyz1, xyz2, points1, emb_lens,
                                       A1, idx_out, wq, iq);
  interp_kernel<<<16384, 256, 0, stream>>>(points2, wq, iq, A1);
  gemm_nt_kernel<false, 13><<<1536, 256, 0, stream>>>(
      A1, KP, W0p, KP, x0, D2_, point_lens, stats);
  apply_bn_gelu_kernel<<<1536, 256, 0, stream>>>(x0, stats, g0, b0, point_lens);
  gemm_nt_kernel<false, 12><<<1536, 256, 0, stream>>>(
      x0, D2_, W1c, D2_, x1, D2_, point_lens, stats + 768);
  apply_bn_out_kernel<<<1536, 256, 0, stream>>>(x1, stats + 768, g1, b1,
                                                point_lens, out);
}